// Round 4
// baseline (389.762 us; speedup 1.0000x reference)
//
#include <hip/hip_runtime.h>

// Decoder: scores[b,m] = sum_e ( sum_d sbj[b,0,d] * W_r[rel[b]][d][e] ) * obj[b,m][e]
// B=1024, D=512, N_OBJ=64, EDGE_COUNT=200. All f32.
//
// Fully fused pipeline:
//   K0 prep: bucket-sort batches by relation into chunks of <=8 (parallel scan).
//   K1 main: per (chunk, 128-col slice): stream W slice once (grouped over <=8
//            batches), LDS-reduce to V_slice, then score the slice against obj
//            and atomicAdd into out. No V round-trip, no inter-block deps;
//            W (213 MB) and obj (128 MB) streams overlap chip-wide.
// out is re-poisoned 0xAA by the harness -> zero it with hipMemsetAsync first.

#define D        512
#define NOBJ     64
#define EDGES    200
#define G        8       // batches per chunk
#define CSPL     4       // column slices (128 cols per block)

__device__ __forceinline__ float4 f4zero() { float4 z; z.x=z.y=z.z=z.w=0.f; return z; }

// ---------------- K0: bucket sort by relation + chunk table ----------------
__global__ __launch_bounds__(256) void prep_kernel(
    const int* __restrict__ rel, int B,
    int* __restrict__ sorted, int* __restrict__ chunk_rel,
    int* __restrict__ chunk_start, int* __restrict__ chunk_cnt,
    int* __restrict__ nchunks)
{
    __shared__ int cnt[256];
    __shared__ int scan[256];
    __shared__ int off[256];
    __shared__ int pos[256];
    __shared__ int nch;
    const int t = threadIdx.x;

    cnt[t] = 0;
    pos[t] = 0;
    if (t == 0) nch = 0;
    __syncthreads();

    for (int b = t; b < B; b += 256) atomicAdd(&cnt[rel[b]], 1);
    __syncthreads();

    // Hillis-Steele inclusive scan over 256 (EDGES padded with zeros)
    int val = cnt[t];
    scan[t] = val;
    __syncthreads();
    #pragma unroll
    for (int o = 1; o < 256; o <<= 1) {
        int v = (t >= o) ? scan[t - o] : 0;
        __syncthreads();
        scan[t] += v;
        __syncthreads();
    }
    off[t] = scan[t] - val;   // exclusive
    __syncthreads();

    for (int b = t; b < B; b += 256) {
        const int r = rel[b];
        const int p = atomicAdd(&pos[r], 1);
        sorted[off[r] + p] = b;
    }

    if (t < EDGES) {
        const int n = cnt[t];
        if (n > 0) {
            const int nc   = (n + G - 1) / G;
            const int base = atomicAdd(&nch, nc);
            for (int k = 0; k < nc; ++k) {
                chunk_rel[base + k]   = t;
                chunk_start[base + k] = off[t] + k * G;
                chunk_cnt[base + k]   = min(G, n - k * G);
            }
        }
    }
    __syncthreads();
    if (t == 0) *nchunks = nch;
}

// ---------------- K1: fused grouped GEMV + score ----------------
// Block = (chunk, 128-col slice). Phase 1: V_slice = sbj_g @ W[:,slice].
// Phase 2: out[b,m] += dot(V_slice[g], obj[b,m,slice]) via atomicAdd.
__global__ __launch_bounds__(256) void main_kernel(
    const float* __restrict__ sbj, const float* __restrict__ obj,
    const float* __restrict__ Wr,  const int* __restrict__ sorted,
    const int* __restrict__ chunk_rel, const int* __restrict__ chunk_start,
    const int* __restrict__ chunk_cnt, const int* __restrict__ nchunks,
    float* __restrict__ out)
{
    const int cid = blockIdx.x >> 2;
    if (cid >= *nchunks) return;
    const int colbase = (blockIdx.x & 3) * 128;
    const int t      = threadIdx.x;
    const int lane32 = t & 31;     // float4 lane -> 4 cols of the slice
    const int rg     = t >> 5;     // row group 0..7

    // LDS: [0,8192) floats = sbj[8][512] (phase 1a) then partial[8][8][128] (1b)
    //      [8192, 8192+1056) = Vs[8][4*33] (padded to kill bank conflicts)
    __shared__ float lds[8192 + 1056];
    float* s_s   = lds;
    float* s_par = lds;
    float* s_vs  = lds + 8192;

    const int relid = chunk_rel[cid];
    const int start = chunk_start[cid];
    const int cnt   = chunk_cnt[cid];

    int bidx[G];
    #pragma unroll
    for (int g = 0; g < G; ++g) bidx[g] = (g < cnt) ? sorted[start + g] : -1;

    // ---- load subjects to LDS ----
    #pragma unroll
    for (int g = 0; g < G; ++g) {
        float2 v2; v2.x = 0.f; v2.y = 0.f;
        if (g < cnt)
            v2 = reinterpret_cast<const float2*>(sbj + (size_t)bidx[g] * D)[t];
        s_s[g * D + 2 * t]     = v2.x;
        s_s[g * D + 2 * t + 1] = v2.y;
    }
    __syncthreads();

    // ---- phase 1: stream W slice, accumulate 8 grouped GEMVs ----
    const float4* __restrict__ W4 =
        reinterpret_cast<const float4*>(Wr) + (size_t)relid * (D * D / 4) + (colbase >> 2) + lane32;

    float4 acc[G];
    #pragma unroll
    for (int g = 0; g < G; ++g) acc[g] = f4zero();

    #pragma unroll 8
    for (int d8 = 0; d8 < D; d8 += 8) {
        const int row = d8 + rg;
        const float4 w = W4[(size_t)row * (D / 4)];
        #pragma unroll
        for (int g = 0; g < G; ++g) {
            const float sg = s_s[g * D + row];
            acc[g].x = fmaf(sg, w.x, acc[g].x);
            acc[g].y = fmaf(sg, w.y, acc[g].y);
            acc[g].z = fmaf(sg, w.z, acc[g].z);
            acc[g].w = fmaf(sg, w.w, acc[g].w);
        }
    }
    __syncthreads();   // subjects consumed; reuse LDS for partials

    #pragma unroll
    for (int g = 0; g < G; ++g)
        reinterpret_cast<float4*>(s_par)[(rg * G + g) * 32 + lane32] = acc[g];
    __syncthreads();

    // ---- reduce 8 row-groups into padded Vs[g][pair*33 + j] ----
    {
        const int col = t & 127;
        const int gg  = t >> 7;
        #pragma unroll
        for (int gi = 0; gi < 4; ++gi) {
            const int g = gg * 4 + gi;
            float s = 0.f;
            #pragma unroll
            for (int r = 0; r < 8; ++r) s += s_par[(r * G + g) * 128 + col];
            s_vs[g * 132 + (col >> 5) * 33 + (col & 31)] = s;
        }
    }
    __syncthreads();

    // ---- phase 2: score the slice against obj, atomicAdd into out ----
    // thread t: m = t>>2 (0..63), pair = t&3 (32-col quarter of the slice)
    const int pair = t & 3;
    const int m    = t >> 2;

    for (int g = 0; g < cnt; ++g) {
        const float* __restrict__ op =
            obj + (size_t)bidx[g] * NOBJ * D + (size_t)m * D + colbase + pair * 32;
        const float* __restrict__ vp = s_vs + g * 132 + pair * 33;

        float p = 0.f;
        #pragma unroll
        for (int j = 0; j < 8; ++j) {
            const float4 o = reinterpret_cast<const float4*>(op)[j];
            p += vp[4 * j]     * o.x + vp[4 * j + 1] * o.y
               + vp[4 * j + 2] * o.z + vp[4 * j + 3] * o.w;
        }
        p += __shfl_xor(p, 1);
        p += __shfl_xor(p, 2);
        if (pair == 0) atomicAdd(&out[(size_t)bidx[g] * NOBJ + m], p);
    }
}

// ---------------- fallback: fused single-batch kernel (if ws too small) ----------------
__global__ __launch_bounds__(256) void fused_kernel(
    const float* __restrict__ sbj, const float* __restrict__ obj,
    const int* __restrict__ rel, const float* __restrict__ Wr,
    float* __restrict__ out)
{
    const int b = blockIdx.x;
    const int t = threadIdx.x;
    __shared__ float s_lds[D];
    __shared__ float v_lds[D];
    {
        const float2 sv = reinterpret_cast<const float2*>(sbj + (size_t)b * D)[t];
        s_lds[2 * t] = sv.x; s_lds[2 * t + 1] = sv.y;
    }
    __syncthreads();
    const float2* __restrict__ W2 = reinterpret_cast<const float2*>(Wr + (size_t)rel[b] * D * D);
    float acc0 = 0.f, acc1 = 0.f;
    #pragma unroll 8
    for (int d = 0; d < D; ++d) {
        const float sd = s_lds[d];
        const float2 w = W2[d * (D / 2) + t];
        acc0 = fmaf(sd, w.x, acc0); acc1 = fmaf(sd, w.y, acc1);
    }
    v_lds[2 * t] = acc0; v_lds[2 * t + 1] = acc1;
    __syncthreads();
    const int wave = t >> 6, lane = t & 63;
    float vreg[8];
    #pragma unroll
    for (int k = 0; k < 8; ++k) vreg[k] = v_lds[lane * 8 + k];
    const float* __restrict__ objb = obj + (size_t)b * NOBJ * D;
    #pragma unroll 4
    for (int j = 0; j < 16; ++j) {
        const int mm = wave * 16 + j;
        const float4* __restrict__ o4 = reinterpret_cast<const float4*>(objb + (size_t)mm * D);
        const float4 a = o4[lane * 2];
        const float4 c = o4[lane * 2 + 1];
        float p = vreg[0]*a.x + vreg[1]*a.y + vreg[2]*a.z + vreg[3]*a.w
                + vreg[4]*c.x + vreg[5]*c.y + vreg[6]*c.z + vreg[7]*c.w;
        #pragma unroll
        for (int off = 32; off > 0; off >>= 1) p += __shfl_down(p, off, 64);
        if (lane == 0) out[(size_t)b * NOBJ + mm] = p;
    }
}

extern "C" void kernel_launch(void* const* d_in, const int* in_sizes, int n_in,
                              void* d_out, int out_size, void* d_ws, size_t ws_size,
                              hipStream_t stream) {
    const float* sbj = (const float*)d_in[0];   // [B,1,512]
    const float* obj = (const float*)d_in[1];   // [B,64,512]
    const int*   rel = (const int*)d_in[2];     // [B]
    const float* Wr  = (const float*)d_in[3];   // [200,512,512]
    float*       out = (float*)d_out;           // [B,64]
    const int B = in_sizes[2];

    const int maxch = B / G + EDGES;            // bound on sum ceil(n_r/G)

    // workspace layout (no V buffer needed anymore)
    const size_t offSorted = 0;
    const size_t offCRel   = offSorted + (size_t)B * 4;
    const size_t offCStart = offCRel   + (size_t)maxch * 4;
    const size_t offCCnt   = offCStart + (size_t)maxch * 4;
    const size_t offNCh    = offCCnt   + (size_t)maxch * 4;
    const size_t needed    = offNCh + 64;

    if (ws_size < needed) {
        fused_kernel<<<dim3(B), dim3(256), 0, stream>>>(sbj, obj, rel, Wr, out);
        return;
    }

    char* ws = (char*)d_ws;
    int* sorted      = (int*)(ws + offSorted);
    int* chunk_rel   = (int*)(ws + offCRel);
    int* chunk_start = (int*)(ws + offCStart);
    int* chunk_cnt   = (int*)(ws + offCCnt);
    int* nchunks     = (int*)(ws + offNCh);

    // out is poisoned 0xAA before every launch; atomicAdd accumulation needs zeros
    hipMemsetAsync(out, 0, (size_t)out_size * sizeof(float), stream);

    prep_kernel<<<dim3(1), dim3(256), 0, stream>>>(rel, B, sorted, chunk_rel,
                                                   chunk_start, chunk_cnt, nchunks);
    main_kernel<<<dim3(CSPL * maxch), dim3(256), 0, stream>>>(sbj, obj, Wr, sorted,
                                                              chunk_rel, chunk_start,
                                                              chunk_cnt, nchunks, out);
}